// Round 13
// baseline (440.736 us; speedup 1.0000x reference)
//
#include <hip/hip_runtime.h>
#include <math.h>

#define N_NODES 100000

using bf16x8 = __attribute__((ext_vector_type(8))) short;
using f32x4  = __attribute__((ext_vector_type(4))) float;

static inline size_t align_up(size_t x, size_t a){ return (x + a - 1) & ~(a - 1); }

__device__ __forceinline__ unsigned short f2bf(float f){
  unsigned u = __float_as_uint(f);
  u = (u + 0x7fffu + ((u >> 16) & 1u)) >> 16;
  return (unsigned short)u;
}
__device__ __forceinline__ float bf2f(unsigned short h){
  return __uint_as_float(((unsigned)h) << 16);
}
__device__ __forceinline__ float bf_lo(unsigned u){ return __uint_as_float(u << 16); }
__device__ __forceinline__ float bf_hi(unsigned u){ return __uint_as_float(u & 0xffff0000u); }

// ---------------- zero ----------------
__global__ void k_zero(int* __restrict__ p, int n){
  int i = blockIdx.x*blockDim.x + threadIdx.x;
  if(i < n) p[i] = 0;
}

// ------- count pass: deterministic replica = blockIdx&7, contiguous ranges -------
// correctness never depends on block->XCD mapping; locality does (round-robin).
__global__ void k_count(const int* __restrict__ ei, int* __restrict__ cnt8,
                        int E, int n, int epb){
  __shared__ int s_is64;
  if(threadIdx.x == 0){
    int is64 = 1;
    for(int k=0;k<64;k++){ if(ei[2*k+1] != 0){ is64 = 0; break; } }
    s_is64 = is64;
  }
  __syncthreads();
  int is64 = s_is64;
  int* my = cnt8 + (size_t)(blockIdx.x & 7) * n;
  int lo = blockIdx.x * epb;
  int hi = min(lo + epb, E);
  for(int e = lo + threadIdx.x; e < hi; e += 256){
    int d = is64 ? ei[2*(E + e)] : ei[E + e];
    atomicAdd(&my[d], 1);
  }
}

// ---------------- scan (3-phase) over 8 replicas ----------------
__global__ void k_scan_part(const int* __restrict__ cnt8, int* __restrict__ bsum, int n){
  __shared__ int red[256];
  int b = blockIdx.x, t = threadIdx.x;
  int base = b*1024 + t*4;
  int s = 0;
  #pragma unroll
  for(int k=0;k<4;k++){
    int i = base + k;
    if(i < n){
      #pragma unroll
      for(int r=0;r<8;r++) s += cnt8[(size_t)r*n + i];
    }
  }
  red[t] = s; __syncthreads();
  for(int off=128; off>0; off>>=1){
    if(t < off) red[t] += red[t+off];
    __syncthreads();
  }
  if(t==0) bsum[b] = red[0];
}

__global__ void k_scan_top(int* __restrict__ bsum, int nb){
  __shared__ int sh[128];
  int t = threadIdx.x;
  int v = (t < nb) ? bsum[t] : 0;
  sh[t] = v; __syncthreads();
  int inc = v;
  for(int off=1; off<128; off<<=1){
    int add = (t >= off) ? sh[t-off] : 0;
    __syncthreads();
    inc += add; sh[t] = inc;
    __syncthreads();
  }
  if(t < nb) bsum[t] = inc - v;   // exclusive
}

// overwrites cnt8[r][i] with global base offset for (i, replica r)
__global__ void k_scan_down(int* __restrict__ cnt8, const int* __restrict__ bsum,
                            int* __restrict__ offs, float* __restrict__ dinv, int n, int E){
  __shared__ int sh[256];
  int b = blockIdx.x, t = threadIdx.x;
  int base = b*1024 + t*4;
  int tot[4]; int local = 0;
  #pragma unroll
  for(int k=0;k<4;k++){
    int i = base + k; int s = 0;
    if(i < n){
      #pragma unroll
      for(int r=0;r<8;r++) s += cnt8[(size_t)r*n + i];
    }
    tot[k] = s; local += s;
  }
  sh[t] = local; __syncthreads();
  int inc = local;
  for(int off=1; off<256; off<<=1){
    int add = (t >= off) ? sh[t-off] : 0;
    __syncthreads();
    inc += add; sh[t] = inc;
    __syncthreads();
  }
  int running = bsum[b] + (inc - local);
  #pragma unroll
  for(int k=0;k<4;k++){
    int i = base + k;
    if(i < n){
      offs[i] = running;
      dinv[i] = rsqrtf((float)(tot[k] + 1));   // deg includes self-loop
      int acc = running;
      #pragma unroll
      for(int r=0;r<8;r++){
        int c = cnt8[(size_t)r*n + i];
        cnt8[(size_t)r*n + i] = acc;
        acc += c;
      }
      running += tot[k];
    }
  }
  if(b==0 && t==0) offs[n] = E;
}

// ------- fill: same deterministic replica; slot via atomic on bases; NT store -------
__global__ void k_fill(const int* __restrict__ ei, int* __restrict__ cbase,
                       int* __restrict__ csr, int E, int n, int epb){
  __shared__ int s_is64;
  if(threadIdx.x == 0){
    int is64 = 1;
    for(int k=0;k<64;k++){ if(ei[2*k+1] != 0){ is64 = 0; break; } }
    s_is64 = is64;
  }
  __syncthreads();
  int is64 = s_is64;
  int* my = cbase + (size_t)(blockIdx.x & 7) * n;
  int lo = blockIdx.x * epb;
  int hi = min(lo + epb, E);
  for(int e = lo + threadIdx.x; e < hi; e += 256){
    int s, d;
    if(is64){ s = ei[2*e]; d = ei[2*(E + e)]; }
    else    { s = ei[e];   d = ei[E + e]; }
    int pos = atomicAdd(&my[d], 1);
    __builtin_nontemporal_store(s, &csr[pos]);
  }
}

// ------- W1 -> fragment-ordered split-bf16 (hi/lo), K padded to 192 -------
__global__ void k_prep_w1(const float* __restrict__ w1, unsigned short* __restrict__ w1b){
  int id = blockIdx.x*blockDim.x + threadIdx.x;
  if(id >= 6*8*64) return;
  int lane = id & 63;
  int st = id >> 6;
  int s = st >> 3, t = st & 7;
  int g = lane >> 4;
  int nn = t*16 + (lane & 15);
  unsigned short* dst = w1b + (size_t)((s*8 + t)*64 + lane)*16;
  #pragma unroll
  for(int j=0;j<8;j++){
    int k = s*32 + g*8 + j;
    float v = (k < 165) ? w1[(size_t)k*128 + nn] : 0.f;
    unsigned short hi = f2bf(v);
    unsigned short lo = f2bf(v - bf2f(hi));
    dst[j] = hi; dst[8+j] = lo;
  }
}

// ------- GEMM via MFMA, x staged through LDS coalesced -------
__global__ __launch_bounds__(256) void k_gemm_mfma(const float* __restrict__ x,
                                                   const unsigned short* __restrict__ w1b,
                                                   const float* __restrict__ dinv,
                                                   unsigned short* __restrict__ hsc, int n){
  __shared__ float xs[64*172];
  int t = threadIdx.x;
  int rowbase = blockIdx.x*64;
  int nrow = min(64, n - rowbase);
  int nfl = nrow * 165;
  const float* xblk = x + (size_t)rowbase*165;
  for(int f = t; f < nfl; f += 256){
    int r = f / 165;
    int c = f - r*165;
    xs[r*172 + c] = xblk[f];
  }
  __syncthreads();

  int lane = threadIdx.x & 63;
  int w    = threadIdx.x >> 6;
  int m    = lane & 15;
  int g    = lane >> 4;
  int row  = rowbase + w*16 + m;
  const float* xr = xs + (w*16 + m)*172;
  const bf16x8* wb = (const bf16x8*)w1b;

  f32x4 acc[8];
  #pragma unroll
  for(int q=0;q<8;q++){ acc[q][0]=0.f; acc[q][1]=0.f; acc[q][2]=0.f; acc[q][3]=0.f; }

  #pragma unroll
  for(int s=0;s<6;s++){
    int k0 = s*32 + g*8;
    float v[8];
    if(s < 5){
      #pragma unroll
      for(int j=0;j<8;j++) v[j] = xr[k0+j];
    }else{
      #pragma unroll
      for(int j=0;j<8;j++){ int k = k0+j; v[j] = (k < 165) ? xr[k] : 0.f; }
    }
    bf16x8 ah, al;
    #pragma unroll
    for(int j=0;j<8;j++){
      unsigned short hi = f2bf(v[j]);
      ah[j] = (short)hi;
      al[j] = (short)f2bf(v[j] - bf2f(hi));
    }
    #pragma unroll
    for(int q=0;q<8;q++){
      int bidx = ((s*8 + q)*64 + lane)*2;
      bf16x8 bh = wb[bidx];
      bf16x8 bl = wb[bidx + 1];
      acc[q] = __builtin_amdgcn_mfma_f32_16x16x32_bf16(bh, ah, acc[q], 0, 0, 0);
      acc[q] = __builtin_amdgcn_mfma_f32_16x16x32_bf16(bh, al, acc[q], 0, 0, 0);
      acc[q] = __builtin_amdgcn_mfma_f32_16x16x32_bf16(bl, ah, acc[q], 0, 0, 0);
    }
  }

  if(row < n){
    float di = dinv[row];
    unsigned* hp = (unsigned*)(hsc + (size_t)row*128);
    #pragma unroll
    for(int q=0;q<8;q++){
      unsigned short q0 = f2bf(acc[q][0]*di);
      unsigned short q1 = f2bf(acc[q][1]*di);
      unsigned short q2 = f2bf(acc[q][2]*di);
      unsigned short q3 = f2bf(acc[q][3]*di);
      int nbase = q*16 + g*4;
      hp[(nbase>>1)    ] = (unsigned)q0 | ((unsigned)q1 << 16);
      hp[(nbase>>1) + 1] = (unsigned)q2 | ((unsigned)q3 << 16);
    }
  }
}

// ------- layer-1 aggregation + relu + dot(W4) fused; emits g = dinv*h2 -------
// wave per node; quarter-wave (16 lanes x uint4 = 256B row) per edge,
// unroll x4 => 16 independent row-gathers in flight per wave
__global__ __launch_bounds__(256) void k_agg1(const unsigned short* __restrict__ hsc,
                                              const int* __restrict__ offs,
                                              const int* __restrict__ csr,
                                              const float* __restrict__ dinv,
                                              const float* __restrict__ b1,
                                              const float* __restrict__ w4,
                                              float* __restrict__ g, int n){
  int wv = threadIdx.x >> 6;
  int lane = threadIdx.x & 63;
  int q   = lane >> 4;
  int sub = lane & 15;
  int i = blockIdx.x * 4 + wv;
  if(i >= n) return;

  float di = dinv[i];
  int s0 = offs[i], s1 = offs[i+1];
  const uint4* base = (const uint4*)hsc;   // row = 16 uint4

  float a0=0.f,a1=0.f,a2=0.f,a3=0.f,a4=0.f,a5=0.f,a6=0.f,a7=0.f;
  int e = s0 + q;
  for(; e + 12 < s1; e += 16){
    int i0=csr[e], i1=csr[e+4], i2=csr[e+8], i3=csr[e+12];
    uint4 u0 = base[(size_t)i0*16 + sub];
    uint4 u1 = base[(size_t)i1*16 + sub];
    uint4 u2 = base[(size_t)i2*16 + sub];
    uint4 u3 = base[(size_t)i3*16 + sub];
    a0 += (bf_lo(u0.x)+bf_lo(u1.x)) + (bf_lo(u2.x)+bf_lo(u3.x));
    a1 += (bf_hi(u0.x)+bf_hi(u1.x)) + (bf_hi(u2.x)+bf_hi(u3.x));
    a2 += (bf_lo(u0.y)+bf_lo(u1.y)) + (bf_lo(u2.y)+bf_lo(u3.y));
    a3 += (bf_hi(u0.y)+bf_hi(u1.y)) + (bf_hi(u2.y)+bf_hi(u3.y));
    a4 += (bf_lo(u0.z)+bf_lo(u1.z)) + (bf_lo(u2.z)+bf_lo(u3.z));
    a5 += (bf_hi(u0.z)+bf_hi(u1.z)) + (bf_hi(u2.z)+bf_hi(u3.z));
    a6 += (bf_lo(u0.w)+bf_lo(u1.w)) + (bf_lo(u2.w)+bf_lo(u3.w));
    a7 += (bf_hi(u0.w)+bf_hi(u1.w)) + (bf_hi(u2.w)+bf_hi(u3.w));
  }
  for(; e + 4 < s1; e += 8){
    uint4 u0 = base[(size_t)csr[e]*16 + sub];
    uint4 u1 = base[(size_t)csr[e+4]*16 + sub];
    a0 += bf_lo(u0.x)+bf_lo(u1.x);  a1 += bf_hi(u0.x)+bf_hi(u1.x);
    a2 += bf_lo(u0.y)+bf_lo(u1.y);  a3 += bf_hi(u0.y)+bf_hi(u1.y);
    a4 += bf_lo(u0.z)+bf_lo(u1.z);  a5 += bf_hi(u0.z)+bf_hi(u1.z);
    a6 += bf_lo(u0.w)+bf_lo(u1.w);  a7 += bf_hi(u0.w)+bf_hi(u1.w);
  }
  if(e < s1){
    uint4 u0 = base[(size_t)csr[e]*16 + sub];
    a0 += bf_lo(u0.x);  a1 += bf_hi(u0.x);
    a2 += bf_lo(u0.y);  a3 += bf_hi(u0.y);
    a4 += bf_lo(u0.z);  a5 += bf_hi(u0.z);
    a6 += bf_lo(u0.w);  a7 += bf_hi(u0.w);
  }
  if(q == 0){   // self-loop once
    uint4 uS = base[(size_t)i*16 + sub];
    a0 += bf_lo(uS.x);  a1 += bf_hi(uS.x);
    a2 += bf_lo(uS.y);  a3 += bf_hi(uS.y);
    a4 += bf_lo(uS.z);  a5 += bf_hi(uS.z);
    a6 += bf_lo(uS.w);  a7 += bf_hi(uS.w);
  }
  // combine quarters
  a0 += __shfl_xor(a0,16,64); a0 += __shfl_xor(a0,32,64);
  a1 += __shfl_xor(a1,16,64); a1 += __shfl_xor(a1,32,64);
  a2 += __shfl_xor(a2,16,64); a2 += __shfl_xor(a2,32,64);
  a3 += __shfl_xor(a3,16,64); a3 += __shfl_xor(a3,32,64);
  a4 += __shfl_xor(a4,16,64); a4 += __shfl_xor(a4,32,64);
  a5 += __shfl_xor(a5,16,64); a5 += __shfl_xor(a5,32,64);
  a6 += __shfl_xor(a6,16,64); a6 += __shfl_xor(a6,32,64);
  a7 += __shfl_xor(a7,16,64); a7 += __shfl_xor(a7,32,64);

  int f = sub*8;
  float4 bL = *(const float4*)&b1[f];
  float4 bH = *(const float4*)&b1[f+4];
  float4 wL = *(const float4*)&w4[f];
  float4 wH = *(const float4*)&w4[f+4];
  float p = fmaxf(di*a0 + bL.x, 0.f)*wL.x
          + fmaxf(di*a1 + bL.y, 0.f)*wL.y
          + fmaxf(di*a2 + bL.z, 0.f)*wL.z
          + fmaxf(di*a3 + bL.w, 0.f)*wL.w
          + fmaxf(di*a4 + bH.x, 0.f)*wH.x
          + fmaxf(di*a5 + bH.y, 0.f)*wH.y
          + fmaxf(di*a6 + bH.z, 0.f)*wH.z
          + fmaxf(di*a7 + bH.w, 0.f)*wH.w;
  p += __shfl_xor(p, 1, 64);
  p += __shfl_xor(p, 2, 64);
  p += __shfl_xor(p, 4, 64);
  p += __shfl_xor(p, 8, 64);
  if(lane == 0) g[i] = di * p;     // g = dinv * h2
}

// ------- layer-2 aggregation via CSR gather + sigmoid (8 lanes/node) -------
__global__ void k_agg2c(const float* __restrict__ g, const int* __restrict__ offs,
                        const int* __restrict__ csr, const float* __restrict__ dinv,
                        const float* __restrict__ b4, float* __restrict__ out, int n){
  int lane = threadIdx.x & 63;
  int wv   = threadIdx.x >> 6;
  int sub  = lane & 7;
  int i = blockIdx.x*32 + wv*8 + (lane >> 3);
  if(i >= n) return;
  int s1 = offs[i+1];
  float p = 0.f;
  for(int e = offs[i] + sub; e < s1; e += 8) p += g[csr[e]];
  p += __shfl_xor(p, 4, 8);
  p += __shfl_xor(p, 2, 8);
  p += __shfl_xor(p, 1, 8);
  if(sub == 0){
    float di = dinv[i];
    float z = di*(p + g[i]) + b4[0];
    out[i] = 1.f/(1.f+expf(-z));
  }
}

// ---------------- launch ----------------
extern "C" void kernel_launch(void* const* d_in, const int* in_sizes, int n_in,
                              void* d_out, int out_size, void* d_ws, size_t ws_size,
                              hipStream_t stream){
  const float* x  = (const float*)d_in[0];
  const int*   ei = (const int*)d_in[1];
  const float* w1 = (const float*)d_in[2];
  const float* b1 = (const float*)d_in[3];
  const float* w4 = (const float*)d_in[4];
  const float* b4 = (const float*)d_in[5];
  float* out = (float*)d_out;

  const int n = N_NODES;
  const int E = in_sizes[1] / 2;
  const int epb = (E + 2047) / 2048;   // edges per block, contiguous ranges

  char* ws = (char*)d_ws;
  size_t off = 0;
  auto carve = [&](size_t bytes)->void*{
    void* p = ws + off; off = align_up(off + bytes, 256); return p;
  };
  int*   cnt8 = (int*)carve((size_t)8*n*4);     // per-replica counts -> bases
  int*   offs = (int*)carve((size_t)(n+1)*4);
  int*   bsum = (int*)carve(128*4);
  float* dinv = (float*)carve((size_t)n*4);
  int*   csr  = (int*)carve((size_t)E*4);
  unsigned short* w1b = (unsigned short*)carve((size_t)6*8*64*16*2);
  unsigned short* hsc = (unsigned short*)carve((size_t)n*128*2);
  float* g    = (float*)carve((size_t)n*4);
  (void)ws_size;

  int nb = (n + 1023) / 1024;   // 98

  k_zero     <<<(8*n+255)/256, 256, 0, stream>>>(cnt8, 8*n);
  k_count    <<<2048, 256, 0, stream>>>(ei, cnt8, E, n, epb);
  k_scan_part<<<nb, 256, 0, stream>>>(cnt8, bsum, n);
  k_scan_top <<<1, 128, 0, stream>>>(bsum, nb);
  k_scan_down<<<nb, 256, 0, stream>>>(cnt8, bsum, offs, dinv, n, E);
  k_fill     <<<2048, 256, 0, stream>>>(ei, cnt8, csr, E, n, epb);
  k_prep_w1  <<<12, 256, 0, stream>>>(w1, w1b);
  k_gemm_mfma<<<(n+63)/64, 256, 0, stream>>>(x, w1b, dinv, hsc, n);
  k_agg1     <<<(n+3)/4, 256, 0, stream>>>(hsc, offs, csr, dinv, b1, w4, g, n);
  k_agg2c    <<<(n+31)/32, 256, 0, stream>>>(g, offs, csr, dinv, b4, out, n);
}

// Round 14
// 323.777 us; speedup vs baseline: 1.3612x; 1.3612x over previous
//
#include <hip/hip_runtime.h>
#include <math.h>

#define N_NODES 100000

using bf16x8 = __attribute__((ext_vector_type(8))) short;
using f32x4  = __attribute__((ext_vector_type(4))) float;

static inline size_t align_up(size_t x, size_t a){ return (x + a - 1) & ~(a - 1); }

__device__ __forceinline__ unsigned short f2bf(float f){
  unsigned u = __float_as_uint(f);
  u = (u + 0x7fffu + ((u >> 16) & 1u)) >> 16;
  return (unsigned short)u;
}
__device__ __forceinline__ float bf2f(unsigned short h){
  return __uint_as_float(((unsigned)h) << 16);
}
__device__ __forceinline__ float bf_lo(unsigned u){ return __uint_as_float(u << 16); }
__device__ __forceinline__ float bf_hi(unsigned u){ return __uint_as_float(u & 0xffff0000u); }

__device__ __forceinline__ int xcd_id(){
  int x;
  asm volatile("s_getreg_b32 %0, hwreg(HW_REG_XCC_ID)" : "=s"(x));
  return x & 7;
}

// ---------------- zero ----------------
__global__ void k_zero(int* __restrict__ p, int n){
  int i = blockIdx.x*blockDim.x + threadIdx.x;
  if(i < n) p[i] = 0;
}

// ------- count into per-XCD replica; rank = (local_rank<<3)|xcd -------
// (measured-good in round 8: atomic stays in issuing XCD's L2)
__global__ void k_convert_count(const int* __restrict__ ei,
                                int* __restrict__ rank, int* __restrict__ cnt8,
                                int E, int n){
  __shared__ int s_is64;
  if(threadIdx.x == 0){
    int is64 = 1;
    for(int k=0;k<64;k++){ if(ei[2*k+1] != 0){ is64 = 0; break; } }
    s_is64 = is64;
  }
  __syncthreads();
  int is64 = s_is64;
  int r = xcd_id();
  int* my = cnt8 + (size_t)r * n;       // replica private to this XCD's L2
  int stride = gridDim.x * blockDim.x;
  for(int e = blockIdx.x*blockDim.x + threadIdx.x; e < E; e += stride){
    int d = is64 ? ei[2*(E + e)] : ei[E + e];
    int local = atomicAdd(&my[d], 1);
    rank[e] = (local << 3) | r;
  }
}

// ---------------- scan (3-phase) over 8 replicas ----------------
__global__ void k_scan_part(const int* __restrict__ cnt8, int* __restrict__ bsum, int n){
  __shared__ int red[256];
  int b = blockIdx.x, t = threadIdx.x;
  int base = b*1024 + t*4;
  int s = 0;
  #pragma unroll
  for(int k=0;k<4;k++){
    int i = base + k;
    if(i < n){
      #pragma unroll
      for(int r=0;r<8;r++) s += cnt8[(size_t)r*n + i];
    }
  }
  red[t] = s; __syncthreads();
  for(int off=128; off>0; off>>=1){
    if(t < off) red[t] += red[t+off];
    __syncthreads();
  }
  if(t==0) bsum[b] = red[0];
}

__global__ void k_scan_top(int* __restrict__ bsum, int nb){
  __shared__ int sh[128];
  int t = threadIdx.x;
  int v = (t < nb) ? bsum[t] : 0;
  sh[t] = v; __syncthreads();
  int inc = v;
  for(int off=1; off<128; off<<=1){
    int add = (t >= off) ? sh[t-off] : 0;
    __syncthreads();
    inc += add; sh[t] = inc;
    __syncthreads();
  }
  if(t < nb) bsum[t] = inc - v;   // exclusive
}

// overwrites cnt8[r][i] with global base offset for (i, replica r)
__global__ void k_scan_down(int* __restrict__ cnt8, const int* __restrict__ bsum,
                            int* __restrict__ offs, float* __restrict__ dinv, int n, int E){
  __shared__ int sh[256];
  int b = blockIdx.x, t = threadIdx.x;
  int base = b*1024 + t*4;
  int tot[4]; int local = 0;
  #pragma unroll
  for(int k=0;k<4;k++){
    int i = base + k; int s = 0;
    if(i < n){
      #pragma unroll
      for(int r=0;r<8;r++) s += cnt8[(size_t)r*n + i];
    }
    tot[k] = s; local += s;
  }
  sh[t] = local; __syncthreads();
  int inc = local;
  for(int off=1; off<256; off<<=1){
    int add = (t >= off) ? sh[t-off] : 0;
    __syncthreads();
    inc += add; sh[t] = inc;
    __syncthreads();
  }
  int running = bsum[b] + (inc - local);
  #pragma unroll
  for(int k=0;k<4;k++){
    int i = base + k;
    if(i < n){
      offs[i] = running;
      dinv[i] = rsqrtf((float)(tot[k] + 1));   // deg includes self-loop
      int acc = running;
      #pragma unroll
      for(int r=0;r<8;r++){
        int c = cnt8[(size_t)r*n + i];
        cnt8[(size_t)r*n + i] = acc;
        acc += c;
      }
      running += tot[k];
    }
  }
  if(b==0 && t==0) offs[n] = E;
}

// ---------------- fill: no atomics; plain cached stores (csr is L2-resident) ----
__global__ void k_fill(const int* __restrict__ ei, const int* __restrict__ rank,
                       const int* __restrict__ cbase, int* __restrict__ csr, int E, int n){
  __shared__ int s_is64;
  if(threadIdx.x == 0){
    int is64 = 1;
    for(int k=0;k<64;k++){ if(ei[2*k+1] != 0){ is64 = 0; break; } }
    s_is64 = is64;
  }
  __syncthreads();
  int is64 = s_is64;
  int stride = gridDim.x * blockDim.x;
  for(int e = blockIdx.x*blockDim.x + threadIdx.x; e < E; e += stride){
    int s, d;
    if(is64){ s = ei[2*e]; d = ei[2*(E + e)]; }
    else    { s = ei[e];   d = ei[E + e]; }
    int rk = rank[e];
    csr[cbase[(size_t)(rk & 7)*n + d] + (rk >> 3)] = s;
  }
}

// ------- W1 -> fragment-ordered split-bf16 (hi/lo), K padded to 192 -------
__global__ void k_prep_w1(const float* __restrict__ w1, unsigned short* __restrict__ w1b){
  int id = blockIdx.x*blockDim.x + threadIdx.x;
  if(id >= 6*8*64) return;
  int lane = id & 63;
  int st = id >> 6;
  int s = st >> 3, t = st & 7;
  int g = lane >> 4;
  int nn = t*16 + (lane & 15);
  unsigned short* dst = w1b + (size_t)((s*8 + t)*64 + lane)*16;
  #pragma unroll
  for(int j=0;j<8;j++){
    int k = s*32 + g*8 + j;
    float v = (k < 165) ? w1[(size_t)k*128 + nn] : 0.f;
    unsigned short hi = f2bf(v);
    unsigned short lo = f2bf(v - bf2f(hi));
    dst[j] = hi; dst[8+j] = lo;
  }
}

// ------- GEMM via MFMA, x staged through LDS coalesced -------
__global__ __launch_bounds__(256) void k_gemm_mfma(const float* __restrict__ x,
                                                   const unsigned short* __restrict__ w1b,
                                                   const float* __restrict__ dinv,
                                                   unsigned short* __restrict__ hsc, int n){
  __shared__ float xs[64*172];
  int t = threadIdx.x;
  int rowbase = blockIdx.x*64;
  int nrow = min(64, n - rowbase);
  int nfl = nrow * 165;
  const float* xblk = x + (size_t)rowbase*165;
  for(int f = t; f < nfl; f += 256){
    int r = f / 165;
    int c = f - r*165;
    xs[r*172 + c] = xblk[f];
  }
  __syncthreads();

  int lane = threadIdx.x & 63;
  int w    = threadIdx.x >> 6;
  int m    = lane & 15;
  int g    = lane >> 4;
  int row  = rowbase + w*16 + m;
  const float* xr = xs + (w*16 + m)*172;
  const bf16x8* wb = (const bf16x8*)w1b;

  f32x4 acc[8];
  #pragma unroll
  for(int q=0;q<8;q++){ acc[q][0]=0.f; acc[q][1]=0.f; acc[q][2]=0.f; acc[q][3]=0.f; }

  #pragma unroll
  for(int s=0;s<6;s++){
    int k0 = s*32 + g*8;
    float v[8];
    if(s < 5){
      #pragma unroll
      for(int j=0;j<8;j++) v[j] = xr[k0+j];
    }else{
      #pragma unroll
      for(int j=0;j<8;j++){ int k = k0+j; v[j] = (k < 165) ? xr[k] : 0.f; }
    }
    bf16x8 ah, al;
    #pragma unroll
    for(int j=0;j<8;j++){
      unsigned short hi = f2bf(v[j]);
      ah[j] = (short)hi;
      al[j] = (short)f2bf(v[j] - bf2f(hi));
    }
    #pragma unroll
    for(int q=0;q<8;q++){
      int bidx = ((s*8 + q)*64 + lane)*2;
      bf16x8 bh = wb[bidx];
      bf16x8 bl = wb[bidx + 1];
      acc[q] = __builtin_amdgcn_mfma_f32_16x16x32_bf16(bh, ah, acc[q], 0, 0, 0);
      acc[q] = __builtin_amdgcn_mfma_f32_16x16x32_bf16(bh, al, acc[q], 0, 0, 0);
      acc[q] = __builtin_amdgcn_mfma_f32_16x16x32_bf16(bl, ah, acc[q], 0, 0, 0);
    }
  }

  if(row < n){
    float di = dinv[row];
    unsigned* hp = (unsigned*)(hsc + (size_t)row*128);
    #pragma unroll
    for(int q=0;q<8;q++){
      unsigned short q0 = f2bf(acc[q][0]*di);
      unsigned short q1 = f2bf(acc[q][1]*di);
      unsigned short q2 = f2bf(acc[q][2]*di);
      unsigned short q3 = f2bf(acc[q][3]*di);
      int nbase = q*16 + g*4;
      hp[(nbase>>1)    ] = (unsigned)q0 | ((unsigned)q1 << 16);
      hp[(nbase>>1) + 1] = (unsigned)q2 | ((unsigned)q3 << 16);
    }
  }
}

// ------- layer-1 aggregation + relu + dot(W4) fused; emits g = dinv*h2 -------
// wave per node; quarter-wave (16 lanes x uint4 = 256B row) per edge,
// unroll x4 => 16 independent row-gathers in flight per wave
__global__ __launch_bounds__(256) void k_agg1(const unsigned short* __restrict__ hsc,
                                              const int* __restrict__ offs,
                                              const int* __restrict__ csr,
                                              const float* __restrict__ dinv,
                                              const float* __restrict__ b1,
                                              const float* __restrict__ w4,
                                              float* __restrict__ g, int n){
  int wv = threadIdx.x >> 6;
  int lane = threadIdx.x & 63;
  int q   = lane >> 4;
  int sub = lane & 15;
  int i = blockIdx.x * 4 + wv;
  if(i >= n) return;

  float di = dinv[i];
  int s0 = offs[i], s1 = offs[i+1];
  const uint4* base = (const uint4*)hsc;   // row = 16 uint4

  float a0=0.f,a1=0.f,a2=0.f,a3=0.f,a4=0.f,a5=0.f,a6=0.f,a7=0.f;
  int e = s0 + q;
  for(; e + 12 < s1; e += 16){
    int i0=csr[e], i1=csr[e+4], i2=csr[e+8], i3=csr[e+12];
    uint4 u0 = base[(size_t)i0*16 + sub];
    uint4 u1 = base[(size_t)i1*16 + sub];
    uint4 u2 = base[(size_t)i2*16 + sub];
    uint4 u3 = base[(size_t)i3*16 + sub];
    a0 += (bf_lo(u0.x)+bf_lo(u1.x)) + (bf_lo(u2.x)+bf_lo(u3.x));
    a1 += (bf_hi(u0.x)+bf_hi(u1.x)) + (bf_hi(u2.x)+bf_hi(u3.x));
    a2 += (bf_lo(u0.y)+bf_lo(u1.y)) + (bf_lo(u2.y)+bf_lo(u3.y));
    a3 += (bf_hi(u0.y)+bf_hi(u1.y)) + (bf_hi(u2.y)+bf_hi(u3.y));
    a4 += (bf_lo(u0.z)+bf_lo(u1.z)) + (bf_lo(u2.z)+bf_lo(u3.z));
    a5 += (bf_hi(u0.z)+bf_hi(u1.z)) + (bf_hi(u2.z)+bf_hi(u3.z));
    a6 += (bf_lo(u0.w)+bf_lo(u1.w)) + (bf_lo(u2.w)+bf_lo(u3.w));
    a7 += (bf_hi(u0.w)+bf_hi(u1.w)) + (bf_hi(u2.w)+bf_hi(u3.w));
  }
  for(; e + 4 < s1; e += 8){
    uint4 u0 = base[(size_t)csr[e]*16 + sub];
    uint4 u1 = base[(size_t)csr[e+4]*16 + sub];
    a0 += bf_lo(u0.x)+bf_lo(u1.x);  a1 += bf_hi(u0.x)+bf_hi(u1.x);
    a2 += bf_lo(u0.y)+bf_lo(u1.y);  a3 += bf_hi(u0.y)+bf_hi(u1.y);
    a4 += bf_lo(u0.z)+bf_lo(u1.z);  a5 += bf_hi(u0.z)+bf_hi(u1.z);
    a6 += bf_lo(u0.w)+bf_lo(u1.w);  a7 += bf_hi(u0.w)+bf_hi(u1.w);
  }
  if(e < s1){
    uint4 u0 = base[(size_t)csr[e]*16 + sub];
    a0 += bf_lo(u0.x);  a1 += bf_hi(u0.x);
    a2 += bf_lo(u0.y);  a3 += bf_hi(u0.y);
    a4 += bf_lo(u0.z);  a5 += bf_hi(u0.z);
    a6 += bf_lo(u0.w);  a7 += bf_hi(u0.w);
  }
  if(q == 0){   // self-loop once
    uint4 uS = base[(size_t)i*16 + sub];
    a0 += bf_lo(uS.x);  a1 += bf_hi(uS.x);
    a2 += bf_lo(uS.y);  a3 += bf_hi(uS.y);
    a4 += bf_lo(uS.z);  a5 += bf_hi(uS.z);
    a6 += bf_lo(uS.w);  a7 += bf_hi(uS.w);
  }
  // combine quarters
  a0 += __shfl_xor(a0,16,64); a0 += __shfl_xor(a0,32,64);
  a1 += __shfl_xor(a1,16,64); a1 += __shfl_xor(a1,32,64);
  a2 += __shfl_xor(a2,16,64); a2 += __shfl_xor(a2,32,64);
  a3 += __shfl_xor(a3,16,64); a3 += __shfl_xor(a3,32,64);
  a4 += __shfl_xor(a4,16,64); a4 += __shfl_xor(a4,32,64);
  a5 += __shfl_xor(a5,16,64); a5 += __shfl_xor(a5,32,64);
  a6 += __shfl_xor(a6,16,64); a6 += __shfl_xor(a6,32,64);
  a7 += __shfl_xor(a7,16,64); a7 += __shfl_xor(a7,32,64);

  int f = sub*8;
  float4 bL = *(const float4*)&b1[f];
  float4 bH = *(const float4*)&b1[f+4];
  float4 wL = *(const float4*)&w4[f];
  float4 wH = *(const float4*)&w4[f+4];
  float p = fmaxf(di*a0 + bL.x, 0.f)*wL.x
          + fmaxf(di*a1 + bL.y, 0.f)*wL.y
          + fmaxf(di*a2 + bL.z, 0.f)*wL.z
          + fmaxf(di*a3 + bL.w, 0.f)*wL.w
          + fmaxf(di*a4 + bH.x, 0.f)*wH.x
          + fmaxf(di*a5 + bH.y, 0.f)*wH.y
          + fmaxf(di*a6 + bH.z, 0.f)*wH.z
          + fmaxf(di*a7 + bH.w, 0.f)*wH.w;
  p += __shfl_xor(p, 1, 64);
  p += __shfl_xor(p, 2, 64);
  p += __shfl_xor(p, 4, 64);
  p += __shfl_xor(p, 8, 64);
  if(lane == 0) g[i] = di * p;     // g = dinv * h2
}

// ------- layer-2 aggregation via CSR gather + sigmoid (8 lanes/node) -------
__global__ void k_agg2c(const float* __restrict__ g, const int* __restrict__ offs,
                        const int* __restrict__ csr, const float* __restrict__ dinv,
                        const float* __restrict__ b4, float* __restrict__ out, int n){
  int lane = threadIdx.x & 63;
  int wv   = threadIdx.x >> 6;
  int sub  = lane & 7;
  int i = blockIdx.x*32 + wv*8 + (lane >> 3);
  if(i >= n) return;
  int s1 = offs[i+1];
  float p = 0.f;
  for(int e = offs[i] + sub; e < s1; e += 8) p += g[csr[e]];
  p += __shfl_xor(p, 4, 8);
  p += __shfl_xor(p, 2, 8);
  p += __shfl_xor(p, 1, 8);
  if(sub == 0){
    float di = dinv[i];
    float z = di*(p + g[i]) + b4[0];
    out[i] = 1.f/(1.f+expf(-z));
  }
}

// ---------------- launch ----------------
extern "C" void kernel_launch(void* const* d_in, const int* in_sizes, int n_in,
                              void* d_out, int out_size, void* d_ws, size_t ws_size,
                              hipStream_t stream){
  const float* x  = (const float*)d_in[0];
  const int*   ei = (const int*)d_in[1];
  const float* w1 = (const float*)d_in[2];
  const float* b1 = (const float*)d_in[3];
  const float* w4 = (const float*)d_in[4];
  const float* b4 = (const float*)d_in[5];
  float* out = (float*)d_out;

  const int n = N_NODES;
  const int E = in_sizes[1] / 2;

  char* ws = (char*)d_ws;
  size_t off = 0;
  auto carve = [&](size_t bytes)->void*{
    void* p = ws + off; off = align_up(off + bytes, 256); return p;
  };
  int*   cnt8 = (int*)carve((size_t)8*n*4);     // per-XCD replicas -> bases
  int*   offs = (int*)carve((size_t)(n+1)*4);
  int*   bsum = (int*)carve(128*4);
  float* dinv = (float*)carve((size_t)n*4);
  int*   rank = (int*)carve((size_t)E*4);
  int*   csr  = (int*)carve((size_t)E*4);
  unsigned short* w1b = (unsigned short*)carve((size_t)6*8*64*16*2);
  unsigned short* hsc = (unsigned short*)carve((size_t)n*128*2);
  float* g    = (float*)carve((size_t)n*4);
  (void)ws_size;

  int nb = (n + 1023) / 1024;   // 98

  k_zero         <<<(8*n+255)/256, 256, 0, stream>>>(cnt8, 8*n);
  k_convert_count<<<2048, 256, 0, stream>>>(ei, rank, cnt8, E, n);
  k_scan_part    <<<nb, 256, 0, stream>>>(cnt8, bsum, n);
  k_scan_top     <<<1, 128, 0, stream>>>(bsum, nb);
  k_scan_down    <<<nb, 256, 0, stream>>>(cnt8, bsum, offs, dinv, n, E);
  k_fill         <<<2048, 256, 0, stream>>>(ei, rank, cnt8, csr, E, n);
  k_prep_w1      <<<12, 256, 0, stream>>>(w1, w1b);
  k_gemm_mfma    <<<(n+63)/64, 256, 0, stream>>>(x, w1b, dinv, hsc, n);
  k_agg1         <<<(n+3)/4, 256, 0, stream>>>(hsc, offs, csr, dinv, b1, w4, g, n);
  k_agg2c        <<<(n+31)/32, 256, 0, stream>>>(g, offs, csr, dinv, b4, out, n);
}